// Round 15
// baseline (371.306 us; speedup 1.0000x reference)
//
#include <hip/hip_runtime.h>
#include <hip/hip_bf16.h>

typedef __attribute__((ext_vector_type(4))) float f32x4;
typedef __attribute__((ext_vector_type(8))) short s16x8;
typedef __attribute__((ext_vector_type(4))) short s16x4;
typedef __attribute__((ext_vector_type(4))) unsigned uintx4;

#define LBS 264   // buf row stride (shorts): 256 + 8 pad
#define VTS 72    // VT row stride (shorts)
#define LOS 132   // lout row stride (f32) — overlays buf exactly (64*132*4 = 64*264*2)

__device__ __forceinline__ unsigned cvt2bf(float a, float b) {
    unsigned r;
    asm("v_cvt_pk_bf16_f32 %0, %1, %2" : "=v"(r) : "v"(a), "v"(b));
    return r;
}

__device__ __forceinline__ s16x4 pk4bf(float a, float b, float c, float d) {
    uint2 t = { cvt2bf(a, b), cvt2bf(c, d) };
    return __builtin_bit_cast(s16x4, t);
}

// [v0,v1,v2,v3] -> [v0,0,v1,0,v2,0,v3,0]: token (4gl+r) at virtual k=8gl+2r of a
// K=32 fragment; zeros at odd k contribute nothing. (Verified R10/R12.)
__device__ __forceinline__ s16x8 expand_z(s16x4 c) {
    uint2 u = __builtin_bit_cast(uint2, c);
    uintx4 r = { u.x & 0xFFFFu, u.x >> 16, u.y & 0xFFFFu, u.y >> 16 };
    return __builtin_bit_cast(s16x8, r);
}

// A-fragment directly from global fp32 row: 8 floats -> 8 bf16
__device__ __forceinline__ s16x8 load_a(const float* rp, int off, bool valid) {
    f32x4 v0 = { 0.f, 0.f, 0.f, 0.f }, v1 = { 0.f, 0.f, 0.f, 0.f };
    if (valid) {
        v0 = *(const f32x4*)(rp + off);
        v1 = *(const f32x4*)(rp + off + 4);
    }
    uintx4 u = { cvt2bf(v0.x, v0.y), cvt2bf(v0.z, v0.w),
                 cvt2bf(v1.x, v1.y), cvt2bf(v1.z, v1.w) };
    return __builtin_bit_cast(s16x8, u);
}

// K0: weights fp32 -> bf16 AND bias+mask table (merged prep)
__global__ void prep_kernel(const float* __restrict__ qw, const float* __restrict__ pw,
                            const float* __restrict__ rpb,
                            short* __restrict__ wqkv, short* __restrict__ wproj,
                            float* __restrict__ bm) {
    int idx = blockIdx.x * blockDim.x + threadIdx.x;
    if (idx < 65536) {
        const float* src = (idx < 49152) ? (qw + idx * 4) : (pw + (idx - 49152) * 4);
        unsigned* dst = (unsigned*)((idx < 49152) ? (wqkv + idx * 4) : (wproj + (idx - 49152) * 4));
        const f32x4 v = *(const f32x4*)src;
        uint2 o = { cvt2bf(v.x, v.y), cvt2bf(v.z, v.w) };
        *(uint2*)dst = o;
    } else {
        int k = idx - 65536;   // bm index: [cls][head][i][j]
        int j = k & 63;
        int i = (k >> 6) & 63;
        int h = (k >> 12) & 7;
        int c = k >> 15;
        int cy = c >> 1, cx = c & 1;
        float v;
        if (j >= 49) {
            v = -1e9f;
        } else {
            int ic = i > 48 ? 48 : i;
            int yi = ic / 7, xi = ic % 7;
            int yj = j / 7, xj = j % 7;
            float bias = rpb[((yi - yj + 6) * 13 + (xi - xj + 6)) * 8 + h];
            int ri = (cy ? (yi < 4 ? 1 : 2) : 0) * 3 + (cx ? (xi < 4 ? 1 : 2) : 0);
            int rj = (cy ? (yj < 4 ? 1 : 2) : 0) * 3 + (cx ? (xj < 4 ? 1 : 2) : 0);
            float mask = (ri != rj) ? -100.0f : 0.0f;
            v = (bias + mask) * 1.4426950408889634f;
        }
        bm[k] = v;
    }
}

// K2: attention. Block = (window, 4-head group). 8 waves = (hl in 0..3, jh in 0..1).
// 3-barrier structure: QKV(direct-global A) -> B1 -> QK^T/softmax -> B2 -> PV -> B3 -> out.
__global__ __launch_bounds__(512, 4)
void attn_kernel(const float* __restrict__ x,
                 const float* __restrict__ qkv_bias,
                 const short* __restrict__ wqkv,
                 const float* __restrict__ bm,
                 unsigned short* __restrict__ la) {
    __shared__ __align__(16) short buf[64 * LBS];   // Q|K -> lout(f32)
    __shared__ __align__(16) short lvt[128 * VTS];  // V^T, 4 heads (local cols 0..127)
    __shared__ float lml[4 * 64];                   // [hl*64 + i] jh0 partial sums

    const int tid  = threadIdx.x;
    const int w    = tid >> 6;        // wave 0..7
    const int lane = tid & 63;
    const int il   = lane & 15;
    const int gl   = lane >> 4;
    const int hl   = w >> 1;          // head-local 0..3
    const int jh   = w & 1;           // key-half

    const int hg  = blockIdx.x & 1;
    const int win = blockIdx.x >> 1;
    const int wid = win & 63;
    const int b   = win >> 6;
    const int wy  = wid >> 3, wx = wid & 7;

    // per-lane x row pointers for A-fragments (rows mi*16 + il), computed once
    const float* rp[4];
    #pragma unroll
    for (int mi = 0; mi < 4; mi++) {
        int t = mi * 16 + il;
        int tc = t > 48 ? 48 : t;
        int ty = tc / 7, tx = tc % 7;
        int R = wy * 7 + ty + 3; if (R >= 56) R -= 56;
        int C = wx * 7 + tx + 3; if (C >= 56) C -= 56;
        rp[mi] = x + (((b * 56 + R) * 56 + C) << 8);
    }
    const bool v3 = (il == 0);   // row 48+il valid only for il==0

    // ---------------- QKV GEMM: A-frags direct from global x ----------------
    {
        f32x4 acc[4][3];
        #pragma unroll
        for (int mi = 0; mi < 4; mi++)
            #pragma unroll
            for (int t = 0; t < 3; t++) acc[mi][t] = (f32x4){0.f, 0.f, 0.f, 0.f};
        for (int k0 = 0; k0 < 256; k0 += 32) {
            s16x8 a[4];
            a[0] = load_a(rp[0], k0 + 8 * gl, true);
            a[1] = load_a(rp[1], k0 + 8 * gl, true);
            a[2] = load_a(rp[2], k0 + 8 * gl, true);
            a[3] = load_a(rp[3], k0 + 8 * gl, v3);
            #pragma unroll
            for (int t = 0; t < 3; t++) {
                s16x8 bfr = *(const s16x8*)(wqkv + (t * 256 + hg * 128 + 16 * w + il) * 256 + k0 + 8 * gl);
                #pragma unroll
                for (int mi = 0; mi < 4; mi++)
                    acc[mi][t] = __builtin_amdgcn_mfma_f32_16x16x32_bf16(a[mi], bfr, acc[mi][t], 0, 0, 0);
            }
        }
        // V -> lvt (transposed; row = local v-col, col = token)
        {
            float bv = qkv_bias[512 + hg * 128 + 16 * w + il];
            #pragma unroll
            for (int mi = 0; mi < 4; mi++)
                *(s16x4*)&lvt[(16 * w + il) * VTS + mi * 16 + gl * 4] =
                    pk4bf(acc[mi][2][0] + bv, acc[mi][2][1] + bv,
                          acc[mi][2][2] + bv, acc[mi][2][3] + bv);
        }
        // Q|K -> buf (no prior role; no barrier needed before writes)
        {
            const float QSCL = 0.17677669529663687f * 1.4426950408889634f;
            float bq_ = qkv_bias[hg * 128 + 16 * w + il];
            float bk_ = qkv_bias[256 + hg * 128 + 16 * w + il];
            #pragma unroll
            for (int mi = 0; mi < 4; mi++)
                #pragma unroll
                for (int r = 0; r < 4; r++) {
                    int row = mi * 16 + gl * 4 + r;
                    unsigned u = cvt2bf((acc[mi][0][r] + bq_) * QSCL, acc[mi][1][r] + bk_);
                    buf[row * LBS + 16 * w + il] = (short)u;                 // Q local col
                    buf[row * LBS + 128 + 16 * w + il] = (short)(u >> 16);   // K local col
                }
        }
    }
    // bias+mask C-init loads issued BEFORE the barrier: latency hides in drain
    const int cls = ((wy == 7) ? 2 : 0) + ((wx == 7) ? 1 : 0);
    const float* bmp = bm + ((cls * 8 + hg * 4 + hl) * 64) * 64;
    f32x4 s[2][4];
    #pragma unroll
    for (int mi = 0; mi < 2; mi++)
        #pragma unroll
        for (int ni = 0; ni < 4; ni++)
            s[mi][ni] = *(const f32x4*)&bmp[(ni * 16 + il) * 64 + jh * 32 + mi * 16 + gl * 4];
    __syncthreads();   // B1: Q,K,VT published

    // ---------------- attention: wave (hl, jh), keys [32jh, 32jh+32) --------
    {
        s16x8 ak[2];
        #pragma unroll
        for (int mi = 0; mi < 2; mi++)
            ak[mi] = *(const s16x8*)&buf[(jh * 32 + mi * 16 + il) * LBS + 128 + hl * 32 + 8 * gl];
        #pragma unroll
        for (int ni = 0; ni < 4; ni++) {
            s16x8 bq = *(const s16x8*)&buf[(ni * 16 + il) * LBS + hl * 32 + 8 * gl];
            #pragma unroll
            for (int mi = 0; mi < 2; mi++)
                s[mi][ni] = __builtin_amdgcn_mfma_f32_16x16x32_bf16(ak[mi], bq, s[mi][ni], 0, 0, 0);
        }
    }
    // p = 2^s (log2 domain, no max); partial row sums; pack compact
    float l[4] = { 0.f, 0.f, 0.f, 0.f };
    s16x4 pkd[2][4];
    #pragma unroll
    for (int mi = 0; mi < 2; mi++)
        #pragma unroll
        for (int ni = 0; ni < 4; ni++) {
            float p0 = exp2f(s[mi][ni][0]);
            float p1 = exp2f(s[mi][ni][1]);
            float p2 = exp2f(s[mi][ni][2]);
            float p3 = exp2f(s[mi][ni][3]);
            l[ni] += (p0 + p1) + (p2 + p3);
            pkd[mi][ni] = pk4bf(p0, p1, p2, p3);
        }
    #pragma unroll
    for (int ni = 0; ni < 4; ni++) {
        l[ni] += __shfl_xor(l[ni], 16);
        l[ni] += __shfl_xor(l[ni], 32);
    }
    if (jh == 0 && gl == 0) {
        #pragma unroll
        for (int ni = 0; ni < 4; ni++) lml[hl * 64 + ni * 16 + il] = l[ni];
    }
    __syncthreads();   // B2: lml visible; Q|K reads done -> buf free for lout

    // PV: o^T[d][i] += V^T[d][j] P[j][i], zero-shuffle even-k fragments
    f32x4 o[2][4];
    #pragma unroll
    for (int md = 0; md < 2; md++)
        #pragma unroll
        for (int ni = 0; ni < 4; ni++) o[md][ni] = (f32x4){0.f, 0.f, 0.f, 0.f};
    #pragma unroll
    for (int mi = 0; mi < 2; mi++) {
        s16x8 av[2];
        #pragma unroll
        for (int md = 0; md < 2; md++)
            av[md] = expand_z(*(const s16x4*)&lvt[(hl * 32 + md * 16 + il) * VTS + jh * 32 + mi * 16 + 4 * gl]);
        #pragma unroll
        for (int ni = 0; ni < 4; ni++) {
            s16x8 bp = expand_z(pkd[mi][ni]);
            #pragma unroll
            for (int md = 0; md < 2; md++)
                o[md][ni] = __builtin_amdgcn_mfma_f32_16x16x32_bf16(av[md], bp, o[md][ni], 0, 0, 0);
        }
    }
    float* lout = (float*)buf;   // [64][LOS]
    if (jh == 0) {
        #pragma unroll
        for (int md = 0; md < 2; md++)
            #pragma unroll
            for (int ni = 0; ni < 4; ni++)
                *(f32x4*)&lout[(ni * 16 + il) * LOS + hl * 32 + md * 16 + gl * 4] = o[md][ni];
    }
    __syncthreads();   // B3
    if (jh == 1) {
        float sc[4];
        #pragma unroll
        for (int ni = 0; ni < 4; ni++)
            sc[ni] = __builtin_amdgcn_rcpf(l[ni] + lml[hl * 64 + ni * 16 + il]);
        #pragma unroll
        for (int ni = 0; ni < 4; ni++) {
            int i = ni * 16 + il;
            if (i < 49) {
                #pragma unroll
                for (int md = 0; md < 2; md++) {
                    f32x4 t = *(const f32x4*)&lout[i * LOS + hl * 32 + md * 16 + gl * 4];
                    uint2 pk = { cvt2bf((t.x + o[md][ni][0]) * sc[ni], (t.y + o[md][ni][1]) * sc[ni]),
                                 cvt2bf((t.z + o[md][ni][2]) * sc[ni], (t.w + o[md][ni][3]) * sc[ni]) };
                    *(uint2*)&la[(win * 49 + i) * 256 + hg * 128 + hl * 32 + md * 16 + gl * 4] = pk;
                }
            }
        }
    }
}

// K3: proj GEMM + reverse-roll store. Block = window, 8 waves.
__global__ __launch_bounds__(512, 4)
void proj_kernel(const unsigned short* __restrict__ la,
                 const float* __restrict__ proj_bias,
                 const short* __restrict__ wproj,
                 float* __restrict__ out) {
    __shared__ __align__(16) short buf[64 * LBS];   // la -> fout(bf16)

    const int tid  = threadIdx.x;
    const int w    = tid >> 6;
    const int lane = tid & 63;
    const int il   = lane & 15;
    const int gl   = lane >> 4;

    const int win = blockIdx.x;
    const int wid = win & 63;
    const int b   = win >> 6;
    const int wy  = wid >> 3, wx = wid & 7;

    // stage la (bf16 rows, coalesced, 16B chunks); zero rows 49..63
    for (int i = tid; i < 2048; i += 512) {   // 64 rows x 32 chunks of 8 shorts
        int t = i >> 5, c8 = (i & 31) << 3;
        uintx4 v = (t < 49) ? *(const uintx4*)&la[(win * 49 + t) * 256 + c8]
                            : (uintx4){0u, 0u, 0u, 0u};
        *(uintx4*)&buf[t * LBS + c8] = v;
    }
    __syncthreads();   // (1)

    f32x4 acc[4][2];
    #pragma unroll
    for (int mi = 0; mi < 4; mi++)
        #pragma unroll
        for (int ni = 0; ni < 2; ni++) acc[mi][ni] = (f32x4){0.f, 0.f, 0.f, 0.f};
    for (int k0 = 0; k0 < 256; k0 += 32) {
        s16x8 a[4];
        #pragma unroll
        for (int mi = 0; mi < 4; mi++)
            a[mi] = *(const s16x8*)&buf[(mi * 16 + il) * LBS + k0 + 8 * gl];
        #pragma unroll
        for (int ni = 0; ni < 2; ni++) {
            s16x8 bw = *(const s16x8*)(wproj + (32 * w + 16 * ni + il) * 256 + k0 + 8 * gl);
            #pragma unroll
            for (int mi = 0; mi < 4; mi++)
                acc[mi][ni] = __builtin_amdgcn_mfma_f32_16x16x32_bf16(a[mi], bw, acc[mi][ni], 0, 0, 0);
        }
    }
    __syncthreads();   // (2) la reads done; buf -> fout (bf16)
    #pragma unroll
    for (int ni = 0; ni < 2; ni++) {
        int oc = 32 * w + 16 * ni + il;
        float pb = proj_bias[oc];
        #pragma unroll
        for (int mi = 0; mi < 4; mi++)
            #pragma unroll
            for (int r = 0; r < 4; r++) {
                int t = mi * 16 + gl * 4 + r;
                if (t < 49) {
                    unsigned u = cvt2bf(acc[mi][ni][r] + pb, 0.f);
                    buf[t * LBS + oc] = (short)u;
                }
            }
    }
    __syncthreads();   // (3)
    // coalesced store with reverse roll: full 1KB token rows
    for (int i = tid; i < 1568; i += 512) {   // 49 rows x 32 chunks of 8 floats
        int t = i >> 5, c8 = (i & 31) << 3;
        uintx4 u = *(const uintx4*)&buf[t * LBS + c8];
        f32x4 v0, v1;
        v0.x = __builtin_bit_cast(float, u.x << 16);
        v0.y = __builtin_bit_cast(float, u.x & 0xFFFF0000u);
        v0.z = __builtin_bit_cast(float, u.y << 16);
        v0.w = __builtin_bit_cast(float, u.y & 0xFFFF0000u);
        v1.x = __builtin_bit_cast(float, u.z << 16);
        v1.y = __builtin_bit_cast(float, u.z & 0xFFFF0000u);
        v1.z = __builtin_bit_cast(float, u.w << 16);
        v1.w = __builtin_bit_cast(float, u.w & 0xFFFF0000u);
        int ty = t / 7, tx = t % 7;
        int R = wy * 7 + ty + 3; if (R >= 56) R -= 56;
        int C = wx * 7 + tx + 3; if (C >= 56) C -= 56;
        float* op = out + (((b * 56 + R) * 56 + C) << 8) + c8;
        *(f32x4*)op = v0;
        *(f32x4*)(op + 4) = v1;
    }
}

extern "C" void kernel_launch(void* const* d_in, const int* in_sizes, int n_in,
                              void* d_out, int out_size, void* d_ws, size_t ws_size,
                              hipStream_t stream) {
    const float* x   = (const float*)d_in[0];
    const float* qw  = (const float*)d_in[1];
    const float* qb  = (const float*)d_in[2];
    const float* pw  = (const float*)d_in[3];
    const float* pb  = (const float*)d_in[4];
    const float* rpb = (const float*)d_in[5];

    short* wqkv  = (short*)d_ws;                            // 768*256 bf16
    short* wproj = wqkv + 768 * 256;                        // 256*256 bf16
    float* bmt   = (float*)((char*)d_ws + 524288);          // 4*8*64*64 f32
    unsigned short* lat = (unsigned short*)((char*)d_ws + 2097152);  // 2048*49*256 bf16 = 51.4 MB

    prep_kernel<<<768, 256, 0, stream>>>(qw, pw, rpb, wqkv, wproj, bmt);
    attn_kernel<<<4096, 512, 0, stream>>>(x, qb, wqkv, bmt, lat);
    proj_kernel<<<2048, 512, 0, stream>>>(lat, pb, wproj, (float*)d_out);
}

// Round 16
// 234.819 us; speedup vs baseline: 1.5812x; 1.5812x over previous
//
#include <hip/hip_runtime.h>
#include <hip/hip_bf16.h>

typedef __attribute__((ext_vector_type(4))) float f32x4;
typedef __attribute__((ext_vector_type(8))) short s16x8;
typedef __attribute__((ext_vector_type(4))) short s16x4;
typedef __attribute__((ext_vector_type(4))) unsigned uintx4;

#define LBS 264   // buf row stride (shorts): 256 + 8 pad
#define VTS 72    // VT row stride (shorts)
#define LOS 132   // lout row stride (f32) — overlays buf exactly (64*132*4 = 64*264*2)

__device__ __forceinline__ unsigned cvt2bf(float a, float b) {
    unsigned r;
    asm("v_cvt_pk_bf16_f32 %0, %1, %2" : "=v"(r) : "v"(a), "v"(b));
    return r;
}

__device__ __forceinline__ s16x4 pk4bf(float a, float b, float c, float d) {
    uint2 t = { cvt2bf(a, b), cvt2bf(c, d) };
    return __builtin_bit_cast(s16x4, t);
}

// [v0,v1,v2,v3] -> [v0,0,v1,0,v2,0,v3,0]: token (4gl+r) at virtual k=8gl+2r of a
// K=32 fragment; zeros at odd k contribute nothing. (Verified R10/R12.)
__device__ __forceinline__ s16x8 expand_z(s16x4 c) {
    uint2 u = __builtin_bit_cast(uint2, c);
    uintx4 r = { u.x & 0xFFFFu, u.x >> 16, u.y & 0xFFFFu, u.y >> 16 };
    return __builtin_bit_cast(s16x8, r);
}

// K0: weights fp32 -> bf16 AND bias+mask table (merged prep)
__global__ void prep_kernel(const float* __restrict__ qw, const float* __restrict__ pw,
                            const float* __restrict__ rpb,
                            short* __restrict__ wqkv, short* __restrict__ wproj,
                            float* __restrict__ bm) {
    int idx = blockIdx.x * blockDim.x + threadIdx.x;
    if (idx < 65536) {
        const float* src = (idx < 49152) ? (qw + idx * 4) : (pw + (idx - 49152) * 4);
        unsigned* dst = (unsigned*)((idx < 49152) ? (wqkv + idx * 4) : (wproj + (idx - 49152) * 4));
        const f32x4 v = *(const f32x4*)src;
        uint2 o = { cvt2bf(v.x, v.y), cvt2bf(v.z, v.w) };
        *(uint2*)dst = o;
    } else {
        int k = idx - 65536;   // bm index: [cls][head][i][j]
        int j = k & 63;
        int i = (k >> 6) & 63;
        int h = (k >> 12) & 7;
        int c = k >> 15;
        int cy = c >> 1, cx = c & 1;
        float v;
        if (j >= 49) {
            v = -1e9f;
        } else {
            int ic = i > 48 ? 48 : i;
            int yi = ic / 7, xi = ic % 7;
            int yj = j / 7, xj = j % 7;
            float bias = rpb[((yi - yj + 6) * 13 + (xi - xj + 6)) * 8 + h];
            int ri = (cy ? (yi < 4 ? 1 : 2) : 0) * 3 + (cx ? (xi < 4 ? 1 : 2) : 0);
            int rj = (cy ? (yj < 4 ? 1 : 2) : 0) * 3 + (cx ? (xj < 4 ? 1 : 2) : 0);
            float mask = (ri != rj) ? -100.0f : 0.0f;
            v = (bias + mask) * 1.4426950408889634f;
        }
        bm[k] = v;
    }
}

// K2: attention. Block = (window, 4-head group). 8 waves = (hl in 0..3, jh in 0..1).
// R12-verbatim structure (best measured: 196us) + s_setprio around MFMA clusters.
__global__ __launch_bounds__(512, 2)
void attn_kernel(const float* __restrict__ x,
                 const float* __restrict__ qkv_bias,
                 const short* __restrict__ wqkv,
                 const float* __restrict__ bm,
                 unsigned short* __restrict__ la) {
    __shared__ __align__(16) short buf[64 * LBS];   // x -> Q|K -> lout(f32)
    __shared__ __align__(16) short lvt[128 * VTS];  // V^T, 4 heads (local cols 0..127)
    __shared__ float lml[8 * 64];                   // [(hl*2+jh)*64 + i] partial sums

    const int tid  = threadIdx.x;
    const int w    = tid >> 6;        // wave 0..7
    const int lane = tid & 63;
    const int il   = lane & 15;
    const int gl   = lane >> 4;
    const int hl   = w >> 1;          // head-local 0..3
    const int jh   = w & 1;           // key-half

    const int hg  = blockIdx.x & 1;
    const int win = blockIdx.x >> 1;
    const int wid = win & 63;
    const int b   = win >> 6;
    const int wy  = wid >> 3, wx = wid & 7;

    // ---------------- stage window x (bf16, cols 0..255) --------------------
    for (int i = tid; i < 4096; i += 512) {  // 64 rows x 64 float4 chunks
        int t = i >> 6, c4 = (i & 63) << 2;
        uint2 o;
        if (t < 49) {
            int ty = t / 7, tx = t % 7;
            int R = wy * 7 + ty + 3; if (R >= 56) R -= 56;
            int C = wx * 7 + tx + 3; if (C >= 56) C -= 56;
            const f32x4 v = *(const f32x4*)(x + (((b * 56 + R) * 56 + C) << 8) + c4);
            o.x = cvt2bf(v.x, v.y); o.y = cvt2bf(v.z, v.w);
        } else {
            o.x = 0; o.y = 0;
        }
        *(uint2*)&buf[t * LBS + c4] = o;
    }
    __syncthreads();   // (1)

    // ---------------- QKV GEMM: wave w -> 16 cols each of Q,K,V -------------
    {
        f32x4 acc[4][3];
        #pragma unroll
        for (int mi = 0; mi < 4; mi++)
            #pragma unroll
            for (int t = 0; t < 3; t++) acc[mi][t] = (f32x4){0.f, 0.f, 0.f, 0.f};
        __builtin_amdgcn_s_setprio(1);
        for (int k0 = 0; k0 < 256; k0 += 32) {
            s16x8 a[4];
            #pragma unroll
            for (int mi = 0; mi < 4; mi++)
                a[mi] = *(const s16x8*)&buf[(mi * 16 + il) * LBS + k0 + 8 * gl];
            #pragma unroll
            for (int t = 0; t < 3; t++) {
                s16x8 bfr = *(const s16x8*)(wqkv + (t * 256 + hg * 128 + 16 * w + il) * 256 + k0 + 8 * gl);
                #pragma unroll
                for (int mi = 0; mi < 4; mi++)
                    acc[mi][t] = __builtin_amdgcn_mfma_f32_16x16x32_bf16(a[mi], bfr, acc[mi][t], 0, 0, 0);
            }
        }
        __builtin_amdgcn_s_setprio(0);
        // V -> lvt (transposed; row = local v-col, col = token), disjoint region
        {
            float bv = qkv_bias[512 + hg * 128 + 16 * w + il];
            #pragma unroll
            for (int mi = 0; mi < 4; mi++)
                *(s16x4*)&lvt[(16 * w + il) * VTS + mi * 16 + gl * 4] =
                    pk4bf(acc[mi][2][0] + bv, acc[mi][2][1] + bv,
                          acc[mi][2][2] + bv, acc[mi][2][3] + bv);
        }
        __syncthreads();   // (2) x reads done; buf -> Q|K
        {
            const float QSCL = 0.17677669529663687f * 1.4426950408889634f;
            float bq_ = qkv_bias[hg * 128 + 16 * w + il];
            float bk_ = qkv_bias[256 + hg * 128 + 16 * w + il];
            #pragma unroll
            for (int mi = 0; mi < 4; mi++)
                #pragma unroll
                for (int r = 0; r < 4; r++) {
                    int row = mi * 16 + gl * 4 + r;
                    unsigned u = cvt2bf((acc[mi][0][r] + bq_) * QSCL, acc[mi][1][r] + bk_);
                    buf[row * LBS + 16 * w + il] = (short)u;                 // Q local col
                    buf[row * LBS + 128 + 16 * w + il] = (short)(u >> 16);   // K local col
                }
        }
    }
    __syncthreads();   // (3) Q,K,VT ready

    // ---------------- attention: wave (hl, jh), keys [32jh, 32jh+32) --------
    const int cls = ((wy == 7) ? 2 : 0) + ((wx == 7) ? 1 : 0);
    const float* bmp = bm + ((cls * 8 + hg * 4 + hl) * 64) * 64;

    f32x4 s[2][4];
    #pragma unroll
    for (int mi = 0; mi < 2; mi++)
        #pragma unroll
        for (int ni = 0; ni < 4; ni++)
            s[mi][ni] = *(const f32x4*)&bmp[(ni * 16 + il) * 64 + jh * 32 + mi * 16 + gl * 4];
    {
        s16x8 bq[4];
        #pragma unroll
        for (int ni = 0; ni < 4; ni++)
            bq[ni] = *(const s16x8*)&buf[(ni * 16 + il) * LBS + hl * 32 + 8 * gl];
        __builtin_amdgcn_s_setprio(1);
        #pragma unroll
        for (int mi = 0; mi < 2; mi++) {
            s16x8 ak = *(const s16x8*)&buf[(jh * 32 + mi * 16 + il) * LBS + 128 + hl * 32 + 8 * gl];
            #pragma unroll
            for (int ni = 0; ni < 4; ni++)
                s[mi][ni] = __builtin_amdgcn_mfma_f32_16x16x32_bf16(ak, bq[ni], s[mi][ni], 0, 0, 0);
        }
        __builtin_amdgcn_s_setprio(0);
    }
    // p = 2^s (log2 domain, no max); partial row sums; pack compact
    float l[4] = { 0.f, 0.f, 0.f, 0.f };
    s16x4 pkd[2][4];
    #pragma unroll
    for (int mi = 0; mi < 2; mi++)
        #pragma unroll
        for (int ni = 0; ni < 4; ni++) {
            float p0 = exp2f(s[mi][ni][0]);
            float p1 = exp2f(s[mi][ni][1]);
            float p2 = exp2f(s[mi][ni][2]);
            float p3 = exp2f(s[mi][ni][3]);
            l[ni] += (p0 + p1) + (p2 + p3);
            pkd[mi][ni] = pk4bf(p0, p1, p2, p3);
        }
    #pragma unroll
    for (int ni = 0; ni < 4; ni++) {
        l[ni] += __shfl_xor(l[ni], 16);
        l[ni] += __shfl_xor(l[ni], 32);
    }
    if (jh == 0 && gl == 0) {
        #pragma unroll
        for (int ni = 0; ni < 4; ni++) lml[(hl * 2) * 64 + ni * 16 + il] = l[ni];
    }
    __syncthreads();   // (4) lml visible; Q|K frag reads done -> buf free for lout

    // PV: o^T[d][i] += V^T[d][j] P[j][i], zero-shuffle even-k fragments
    f32x4 o[2][4];
    #pragma unroll
    for (int md = 0; md < 2; md++)
        #pragma unroll
        for (int ni = 0; ni < 4; ni++) o[md][ni] = (f32x4){0.f, 0.f, 0.f, 0.f};
    __builtin_amdgcn_s_setprio(1);
    #pragma unroll
    for (int mi = 0; mi < 2; mi++) {
        s16x8 av[2];
        #pragma unroll
        for (int md = 0; md < 2; md++)
            av[md] = expand_z(*(const s16x4*)&lvt[(hl * 32 + md * 16 + il) * VTS + jh * 32 + mi * 16 + 4 * gl]);
        #pragma unroll
        for (int ni = 0; ni < 4; ni++) {
            s16x8 bp = expand_z(pkd[mi][ni]);
            #pragma unroll
            for (int md = 0; md < 2; md++)
                o[md][ni] = __builtin_amdgcn_mfma_f32_16x16x32_bf16(av[md], bp, o[md][ni], 0, 0, 0);
        }
    }
    __builtin_amdgcn_s_setprio(0);
    float* lout = (float*)buf;   // [64][LOS]
    if (jh == 0) {
        #pragma unroll
        for (int md = 0; md < 2; md++)
            #pragma unroll
            for (int ni = 0; ni < 4; ni++)
                *(f32x4*)&lout[(ni * 16 + il) * LOS + hl * 32 + md * 16 + gl * 4] = o[md][ni];
    }
    __syncthreads();   // (5)
    if (jh == 1) {
        float sc[4];
        #pragma unroll
        for (int ni = 0; ni < 4; ni++)
            sc[ni] = __builtin_amdgcn_rcpf(l[ni] + lml[(hl * 2) * 64 + ni * 16 + il]);
        #pragma unroll
        for (int ni = 0; ni < 4; ni++) {
            int i = ni * 16 + il;
            if (i < 49) {
                #pragma unroll
                for (int md = 0; md < 2; md++) {
                    f32x4 t = *(const f32x4*)&lout[i * LOS + hl * 32 + md * 16 + gl * 4];
                    uint2 pk = { cvt2bf((t.x + o[md][ni][0]) * sc[ni], (t.y + o[md][ni][1]) * sc[ni]),
                                 cvt2bf((t.z + o[md][ni][2]) * sc[ni], (t.w + o[md][ni][3]) * sc[ni]) };
                    *(uint2*)&la[(win * 49 + i) * 256 + hg * 128 + hl * 32 + md * 16 + gl * 4] = pk;
                }
            }
        }
    }
}

// K3: proj GEMM + reverse-roll store. Block = window, 8 waves. (R12 verbatim)
__global__ __launch_bounds__(512, 2)
void proj_kernel(const unsigned short* __restrict__ la,
                 const float* __restrict__ proj_bias,
                 const short* __restrict__ wproj,
                 float* __restrict__ out) {
    __shared__ __align__(16) short buf[64 * LBS];   // la -> fout(bf16)

    const int tid  = threadIdx.x;
    const int w    = tid >> 6;
    const int lane = tid & 63;
    const int il   = lane & 15;
    const int gl   = lane >> 4;

    const int win = blockIdx.x;
    const int wid = win & 63;
    const int b   = win >> 6;
    const int wy  = wid >> 3, wx = wid & 7;

    // stage la (bf16 rows, coalesced, 16B chunks); zero rows 49..63
    for (int i = tid; i < 2048; i += 512) {   // 64 rows x 32 chunks of 8 shorts
        int t = i >> 5, c8 = (i & 31) << 3;
        uintx4 v = (t < 49) ? *(const uintx4*)&la[(win * 49 + t) * 256 + c8]
                            : (uintx4){0u, 0u, 0u, 0u};
        *(uintx4*)&buf[t * LBS + c8] = v;
    }
    __syncthreads();   // (1)

    f32x4 acc[4][2];
    #pragma unroll
    for (int mi = 0; mi < 4; mi++)
        #pragma unroll
        for (int ni = 0; ni < 2; ni++) acc[mi][ni] = (f32x4){0.f, 0.f, 0.f, 0.f};
    __builtin_amdgcn_s_setprio(1);
    for (int k0 = 0; k0 < 256; k0 += 32) {
        s16x8 a[4];
        #pragma unroll
        for (int mi = 0; mi < 4; mi++)
            a[mi] = *(const s16x8*)&buf[(mi * 16 + il) * LBS + k0 + 8 * gl];
        #pragma unroll
        for (int ni = 0; ni < 2; ni++) {
            s16x8 bw = *(const s16x8*)(wproj + (32 * w + 16 * ni + il) * 256 + k0 + 8 * gl);
            #pragma unroll
            for (int mi = 0; mi < 4; mi++)
                acc[mi][ni] = __builtin_amdgcn_mfma_f32_16x16x32_bf16(a[mi], bw, acc[mi][ni], 0, 0, 0);
        }
    }
    __builtin_amdgcn_s_setprio(0);
    __syncthreads();   // (2) la reads done; buf -> fout (bf16)
    #pragma unroll
    for (int ni = 0; ni < 2; ni++) {
        int oc = 32 * w + 16 * ni + il;
        float pb = proj_bias[oc];
        #pragma unroll
        for (int mi = 0; mi < 4; mi++)
            #pragma unroll
            for (int r = 0; r < 4; r++) {
                int t = mi * 16 + gl * 4 + r;
                if (t < 49) {
                    unsigned u = cvt2bf(acc[mi][ni][r] + pb, 0.f);
                    buf[t * LBS + oc] = (short)u;
                }
            }
    }
    __syncthreads();   // (3)
    // coalesced store with reverse roll: full 1KB token rows
    for (int i = tid; i < 1568; i += 512) {   // 49 rows x 32 chunks of 8 floats
        int t = i >> 5, c8 = (i & 31) << 3;
        uintx4 u = *(const uintx4*)&buf[t * LBS + c8];
        f32x4 v0, v1;
        v0.x = __builtin_bit_cast(float, u.x << 16);
        v0.y = __builtin_bit_cast(float, u.x & 0xFFFF0000u);
        v0.z = __builtin_bit_cast(float, u.y << 16);
        v0.w = __builtin_bit_cast(float, u.y & 0xFFFF0000u);
        v1.x = __builtin_bit_cast(float, u.z << 16);
        v1.y = __builtin_bit_cast(float, u.z & 0xFFFF0000u);
        v1.z = __builtin_bit_cast(float, u.w << 16);
        v1.w = __builtin_bit_cast(float, u.w & 0xFFFF0000u);
        int ty = t / 7, tx = t % 7;
        int R = wy * 7 + ty + 3; if (R >= 56) R -= 56;
        int C = wx * 7 + tx + 3; if (C >= 56) C -= 56;
        float* op = out + (((b * 56 + R) * 56 + C) << 8) + c8;
        *(f32x4*)op = v0;
        *(f32x4*)(op + 4) = v1;
    }
}

extern "C" void kernel_launch(void* const* d_in, const int* in_sizes, int n_in,
                              void* d_out, int out_size, void* d_ws, size_t ws_size,
                              hipStream_t stream) {
    const float* x   = (const float*)d_in[0];
    const float* qw  = (const float*)d_in[1];
    const float* qb  = (const float*)d_in[2];
    const float* pw  = (const float*)d_in[3];
    const float* pb  = (const float*)d_in[4];
    const float* rpb = (const float*)d_in[5];

    short* wqkv  = (short*)d_ws;                            // 768*256 bf16
    short* wproj = wqkv + 768 * 256;                        // 256*256 bf16
    float* bmt   = (float*)((char*)d_ws + 524288);          // 4*8*64*64 f32
    unsigned short* lat = (unsigned short*)((char*)d_ws + 2097152);  // 2048*49*256 bf16 = 51.4 MB

    prep_kernel<<<768, 256, 0, stream>>>(qw, pw, rpb, wqkv, wproj, bmt);
    attn_kernel<<<4096, 512, 0, stream>>>(x, qb, wqkv, bmt, lat);
    proj_kernel<<<2048, 512, 0, stream>>>(lat, pb, wproj, (float*)d_out);
}